// Round 1
// baseline (49.615 us; speedup 1.0000x reference)
//
#include <hip/hip_runtime.h>

// NormalComputer: out[b,:,i,j] = normalize(cross(up - down, right - left))
// where up/down/left/right are clamped 4-neighbors of in[b,:,i,j].
// Identity used: sum of the 4 reference cross products == cross(d0-d2, d1-d3)
// == cross(up-down, right-left); the center term cancels, and the idx input
// is never read (indices recomputed from i,j with clamping).

#define HH 1024
#define WW 1024
#define BB 8
#define HW (HH * WW)

__global__ __launch_bounds__(256)
void normal_kernel(const float* __restrict__ in, float* __restrict__ out) {
    const int t = blockIdx.x * blockDim.x + threadIdx.x;  // 0 .. B*HW-1
    const int b = t >> 20;          // t / HW   (HW = 1<<20)
    const int p = t & (HW - 1);
    const int i = p >> 10;          // row
    const int j = p & (WW - 1);     // col

    const int iu = (i > 0)      ? i - 1 : 0;
    const int id = (i < HH - 1) ? i + 1 : HH - 1;
    const int jl = (j > 0)      ? j - 1 : 0;
    const int jr = (j < WW - 1) ? j + 1 : WW - 1;

    const float* base = in + (size_t)b * 3 * HW;

    float a[3], c[3];
#pragma unroll
    for (int ch = 0; ch < 3; ++ch) {
        const float* pl = base + (size_t)ch * HW;
        const float up = pl[iu * WW + j];
        const float dn = pl[id * WW + j];
        const float rt = pl[i * WW + jr];
        const float lf = pl[i * WW + jl];
        a[ch] = up - dn;   // d0 - d2
        c[ch] = rt - lf;   // d1 - d3
    }

    const float nx = a[1] * c[2] - a[2] * c[1];
    const float ny = a[2] * c[0] - a[0] * c[2];
    const float nz = a[0] * c[1] - a[1] * c[0];

    const float norm = sqrtf(nx * nx + ny * ny + nz * nz);
    const float inv  = 1.0f / fmaxf(norm, 1e-6f);

    float* ob = out + (size_t)b * 3 * HW + p;
    ob[0]        = nx * inv;
    ob[HW]       = ny * inv;
    ob[2 * HW]   = nz * inv;
}

extern "C" void kernel_launch(void* const* d_in, const int* in_sizes, int n_in,
                              void* d_out, int out_size, void* d_ws, size_t ws_size,
                              hipStream_t stream) {
    const float* in = (const float*)d_in[0];
    float* out = (float*)d_out;
    const int total = BB * HW;               // 8 * 1M threads
    const int block = 256;
    const int grid = total / block;          // 32768 blocks
    normal_kernel<<<grid, block, 0, stream>>>(in, out);
}